// Round 2
// baseline (393.569 us; speedup 1.0000x reference)
//
#include <hip/hip_runtime.h>
#include <hip/hip_bf16.h>
#include <math.h>

typedef __hip_bfloat16 bf16;
typedef __attribute__((ext_vector_type(4))) float f32x4;
typedef __attribute__((ext_vector_type(8))) short bf16x8s;

#define T_SEQ 4096
#define CTX_REC 4160   // 64 ksum + 64*64 ctx

// ---------------- f32 -> bf16 conversion (vectorized) ----------------
__global__ void cvt_f32_bf16(const float* __restrict__ src, bf16* __restrict__ dst, int n8) {
    int i = blockIdx.x * 256 + threadIdx.x;
    if (i >= n8) return;
    f32x4 a = ((const f32x4*)src)[(size_t)i * 2];
    f32x4 b = ((const f32x4*)src)[(size_t)i * 2 + 1];
    union { bf16 h[8]; uint4 u; } p;
    p.h[0] = __float2bfloat16(a.x); p.h[1] = __float2bfloat16(a.y);
    p.h[2] = __float2bfloat16(a.z); p.h[3] = __float2bfloat16(a.w);
    p.h[4] = __float2bfloat16(b.x); p.h[5] = __float2bfloat16(b.y);
    p.h[6] = __float2bfloat16(b.z); p.h[7] = __float2bfloat16(b.w);
    ((uint4*)dst)[i] = p.u;
}

// ---------------- m97-style bf16 GEMM: C[M,N] = A[M,K] @ B[N,K]^T ----------------
// MODE 0: N=3072 qkv epilogue -> Qb (raw bf16), Kb (exp, bf16), Vb (raw bf16), each [M,1024]
// MODE 1: f32 output [M,N] (d_out is float per reference dtype)
template<int MODE>
__global__ __launch_bounds__(256)
void gemm_bf16(const bf16* __restrict__ A, const bf16* __restrict__ Bm,
               int K, int N,
               bf16* __restrict__ out0, bf16* __restrict__ out1, bf16* __restrict__ out2,
               float* __restrict__ outf)
{
    __shared__ __align__(16) bf16 As[128 * 32];
    __shared__ __align__(16) bf16 Bs[128 * 32];
    const int tid  = threadIdx.x;
    const int lane = tid & 63;
    const int wid  = tid >> 6;
    const int wr   = wid >> 1, wc = wid & 1;
    const int brow = blockIdx.y * 128;
    const int bcol = blockIdx.x * 128;

    f32x4 acc[4][4];
#pragma unroll
    for (int m = 0; m < 4; ++m)
#pragma unroll
        for (int n = 0; n < 4; ++n) acc[m][n] = (f32x4){0.f, 0.f, 0.f, 0.f};

    const int nkt = K >> 5;
    for (int kt = 0; kt < nkt; ++kt) {
#pragma unroll
        for (int it = 0; it < 2; ++it) {
            int idx = it * 256 + tid;
            int r  = idx >> 2;
            int cb = (idx & 3) << 3;
            const bf16* ga = A  + (size_t)(brow + r) * K + kt * 32 + cb;
            __builtin_amdgcn_global_load_lds((const __attribute__((address_space(1))) void*)ga,
                (__attribute__((address_space(3))) void*)&As[idx * 8], 16, 0, 0);
            const bf16* gb = Bm + (size_t)(bcol + r) * K + kt * 32 + cb;
            __builtin_amdgcn_global_load_lds((const __attribute__((address_space(1))) void*)gb,
                (__attribute__((address_space(3))) void*)&Bs[idx * 8], 16, 0, 0);
        }
        __syncthreads();

        bf16x8s a[4], b[4];
        const int kb = (lane >> 4) << 3;
#pragma unroll
        for (int m = 0; m < 4; ++m) {
            int row = wr * 64 + m * 16 + (lane & 15);
            a[m] = *(const bf16x8s*)&As[row * 32 + kb];
        }
#pragma unroll
        for (int n = 0; n < 4; ++n) {
            int col = wc * 64 + n * 16 + (lane & 15);
            b[n] = *(const bf16x8s*)&Bs[col * 32 + kb];
        }
#pragma unroll
        for (int m = 0; m < 4; ++m)
#pragma unroll
            for (int n = 0; n < 4; ++n)
                acc[m][n] = __builtin_amdgcn_mfma_f32_16x16x32_bf16(a[m], b[n], acc[m][n], 0, 0, 0);
        __syncthreads();
    }

    // epilogue: C mapping col=lane&15, row=(lane>>4)*4+r  [m89 verified]
    const int region = bcol >> 10;           // uniform per block (BN=128, regions 1024-aligned)
#pragma unroll
    for (int m = 0; m < 4; ++m) {
        int row = brow + wr * 64 + m * 16 + ((lane >> 4) << 2);
#pragma unroll
        for (int n = 0; n < 4; ++n) {
            int col = bcol + wc * 64 + n * 16 + (lane & 15);
#pragma unroll
            for (int r = 0; r < 4; ++r) {
                float v = acc[m][n][r];
                size_t rr = (size_t)(row + r);
                if (MODE == 1) {
                    outf[rr * N + col] = v;
                } else {
                    int c = col & 1023;
                    if (region == 0)      out0[rr * 1024 + c] = __float2bfloat16(v);
                    else if (region == 1) out1[rr * 1024 + c] = __float2bfloat16(__expf(v));
                    else                  out2[rr * 1024 + c] = __float2bfloat16(v);
                }
            }
        }
    }
}

// ---------------- per-bucket K-sum and K^T V outer product ----------------
// grid: bh*64 + n  (bh = b*16+h), block 256
__global__ __launch_bounds__(256)
void bucket_kv(const bf16* __restrict__ Kb, const bf16* __restrict__ Vb,
               float* __restrict__ ctx)
{
    __shared__ __align__(16) float k_t[64 * 68];
    __shared__ __align__(16) float v_t[64 * 68];
    const int bid = blockIdx.x;
    const int bh = bid >> 6, n = bid & 63;
    const int b = bh >> 4, h = bh & 15;
    const size_t rowbase = (size_t)(b * T_SEQ + n * 64) * 1024 + h * 64;
    const int tid = threadIdx.x;

#pragma unroll
    for (int c = 0; c < 16; ++c) {
        int idx = c * 256 + tid;
        int s = idx >> 6, d = idx & 63;
        k_t[d * 68 + s] = __bfloat162float(Kb[rowbase + (size_t)s * 1024 + d]);
        v_t[d * 68 + s] = __bfloat162float(Vb[rowbase + (size_t)s * 1024 + d]);
    }
    __syncthreads();

    const int e = tid & 63, dg = tid >> 6;
    float acc[16];
#pragma unroll
    for (int i = 0; i < 16; ++i) acc[i] = 0.f;
    for (int s4 = 0; s4 < 16; ++s4) {
        f32x4 vv = *(f32x4*)&v_t[e * 68 + s4 * 4];
#pragma unroll
        for (int i = 0; i < 16; ++i) {
            f32x4 kk = *(f32x4*)&k_t[(dg * 16 + i) * 68 + s4 * 4];
            acc[i] += kk.x * vv.x + kk.y * vv.y + kk.z * vv.z + kk.w * vv.w;
        }
    }
    float* rec = ctx + (size_t)bid * CTX_REC;
#pragma unroll
    for (int i = 0; i < 16; ++i) {
        int d = dg * 16 + i;
        rec[64 + d * 64 + e] = acc[i];
    }
    if (tid < 64) {   // per-d key sum
        float s = 0.f;
        for (int s4 = 0; s4 < 16; ++s4) {
            f32x4 kk = *(f32x4*)&k_t[tid * 68 + s4 * 4];
            s += kk.x + kk.y + kk.z + kk.w;
        }
        rec[tid] = s;
    }
}

// ---------------- exclusive cumsum over buckets, in place ----------------
// grid: (17, 64) -> (chunk, bh)
__global__ void cumsum_excl(float* __restrict__ ctx)
{
    int e = blockIdx.x * 256 + threadIdx.x;
    if (e >= CTX_REC) return;
    float* p = ctx + (size_t)blockIdx.y * 64 * CTX_REC + e;
    float run = 0.f;
#pragma unroll 4
    for (int j = 0; j < 64; ++j) {
        float v = p[(size_t)j * CTX_REC];
        p[(size_t)j * CTX_REC] = run;
        run += v;
    }
}

// ---------------- softmax(q) + den + attn = q @ ctx * Dinv ----------------
__global__ __launch_bounds__(256)
void bucket_attn(const bf16* __restrict__ Qb, const float* __restrict__ ctx,
                 bf16* __restrict__ attn)
{
    __shared__ __align__(16) float q_s[64 * 68];
    __shared__ __align__(16) float c_t[64 * 68];
    __shared__ __align__(16) float ksum[64];
    __shared__ __align__(16) float dinv[64];
    const int bid = blockIdx.x;
    const int bh = bid >> 6, n = bid & 63;
    const int b = bh >> 4, h = bh & 15;
    const size_t rowbase = (size_t)(b * T_SEQ + n * 64) * 1024 + h * 64;
    const int tid = threadIdx.x;
    const float* rec = ctx + (size_t)bid * CTX_REC;

#pragma unroll
    for (int c = 0; c < 16; ++c) {
        int idx = c * 256 + tid;
        int s = idx >> 6, d = idx & 63;
        q_s[s * 68 + d] = __bfloat162float(Qb[rowbase + (size_t)s * 1024 + d]);
        c_t[d * 68 + s] = rec[64 + idx];   // c_t[e][d'] = ctx[d'][e]
    }
    if (tid < 64) ksum[tid] = rec[tid];
    __syncthreads();

    // softmax over each 64-wide row of q_s, * HEAD_DIM^-0.5
    const int lane = tid & 63, w = tid >> 6;
#pragma unroll
    for (int i = 0; i < 16; ++i) {
        int s = w * 16 + i;
        float x = q_s[s * 68 + lane];
        float mx = x;
#pragma unroll
        for (int off = 32; off; off >>= 1) mx = fmaxf(mx, __shfl_xor(mx, off));
        float ex = __expf(x - mx);
        float sm = ex;
#pragma unroll
        for (int off = 32; off; off >>= 1) sm += __shfl_xor(sm, off);
        q_s[s * 68 + lane] = ex / sm * 0.125f;
    }
    __syncthreads();

    if (tid < 64) {
        float den = 0.f;
#pragma unroll
        for (int d4 = 0; d4 < 16; ++d4) {
            f32x4 qq = *(f32x4*)&q_s[tid * 68 + d4 * 4];
            f32x4 kk = *(f32x4*)&ksum[d4 * 4];
            den += qq.x * kk.x + qq.y * kk.y + qq.z * kk.z + qq.w * kk.w;
        }
        dinv[tid] = 1.f / fmaxf(den, 1e-6f);
    }
    __syncthreads();

    const int e = tid & 63, sg = tid >> 6;
    float acc[16];
#pragma unroll
    for (int i = 0; i < 16; ++i) acc[i] = 0.f;
    for (int d4 = 0; d4 < 16; ++d4) {
        f32x4 cc = *(f32x4*)&c_t[e * 68 + d4 * 4];
#pragma unroll
        for (int i = 0; i < 16; ++i) {
            f32x4 qq = *(f32x4*)&q_s[(sg * 16 + i) * 68 + d4 * 4];
            acc[i] += qq.x * cc.x + qq.y * cc.y + qq.z * cc.z + qq.w * cc.w;
        }
    }
#pragma unroll
    for (int i = 0; i < 16; ++i) {
        int s = sg * 16 + i;
        attn[rowbase + (size_t)s * 1024 + e] = __float2bfloat16(acc[i] * dinv[s]);
    }
}

// ---------------- launch ----------------
extern "C" void kernel_launch(void* const* d_in, const int* in_sizes, int n_in,
                              void* d_out, int out_size, void* d_ws, size_t ws_size,
                              hipStream_t stream)
{
    const float* x    = (const float*)d_in[0];
    const float* Wqkv = (const float*)d_in[1];
    const float* Wout = (const float*)d_in[2];

    char* ws = (char*)d_ws;
    size_t off = 0;
    auto alloc = [&](size_t bytes) { void* p = ws + off; off += (bytes + 255) & ~(size_t)255; return p; };
    bf16*  xb    = (bf16*)alloc((size_t)16384 * 1024 * 2);
    bf16*  wqkvb = (bf16*)alloc((size_t)3072 * 1024 * 2);
    bf16*  woutb = (bf16*)alloc((size_t)1024 * 1024 * 2);
    bf16*  Qb    = (bf16*)alloc((size_t)16384 * 1024 * 2);
    bf16*  Kb    = (bf16*)alloc((size_t)16384 * 1024 * 2);
    bf16*  Vb    = (bf16*)alloc((size_t)16384 * 1024 * 2);
    float* ctx   = (float*)alloc((size_t)64 * 64 * CTX_REC * 4);
    bf16*  attnb = xb;                       // xb dead after GEMM1 -> reuse
    float* outf  = (float*)d_out;            // reference output dtype is float32

    cvt_f32_bf16<<<dim3(16384 * 1024 / 8 / 256), 256, 0, stream>>>(x, xb, 16384 * 1024 / 8);
    cvt_f32_bf16<<<dim3(3072 * 1024 / 8 / 256), 256, 0, stream>>>(Wqkv, wqkvb, 3072 * 1024 / 8);
    cvt_f32_bf16<<<dim3(1024 * 1024 / 8 / 256), 256, 0, stream>>>(Wout, woutb, 1024 * 1024 / 8);

    gemm_bf16<0><<<dim3(24, 128), 256, 0, stream>>>(xb, wqkvb, 1024, 3072, Qb, Kb, Vb, nullptr);
    bucket_kv<<<dim3(4096), 256, 0, stream>>>(Kb, Vb, ctx);
    cumsum_excl<<<dim3(17, 64), 256, 0, stream>>>(ctx);
    bucket_attn<<<dim3(4096), 256, 0, stream>>>(Qb, ctx, attnb);
    gemm_bf16<1><<<dim3(8, 128), 256, 0, stream>>>(attnb, woutb, 1024, 1024, nullptr, nullptr, nullptr, outf);
}

// Round 3
// 327.242 us; speedup vs baseline: 1.2027x; 1.2027x over previous
//
#include <hip/hip_runtime.h>
#include <hip/hip_bf16.h>
#include <math.h>

typedef __hip_bfloat16 bf16;
typedef __attribute__((ext_vector_type(4))) float f32x4;
typedef __attribute__((ext_vector_type(8))) short bf16x8s;

#define T_SEQ 4096

static __device__ __forceinline__ float bf2f(short u) {
    return __uint_as_float(((unsigned int)(unsigned short)u) << 16);
}
static __device__ __forceinline__ short f2bf(float f) {
    bf16 h = __float2bfloat16(f);
    union { bf16 b; short s; } c; c.b = h; return c.s;
}
// swizzled LDS layout for [64 rows][64 bf16 cols]: elem (r,c) at r*64 + ((c>>3 ^ f(r))<<3) + (c&7)
static __device__ __forceinline__ int swz_f(int r) { return (r & 7) ^ (r >> 3); }

// ---------------- f32 -> bf16 conversion (vectorized) ----------------
__global__ void cvt_f32_bf16(const float* __restrict__ src, bf16* __restrict__ dst, int n8) {
    int i = blockIdx.x * 256 + threadIdx.x;
    if (i >= n8) return;
    f32x4 a = ((const f32x4*)src)[(size_t)i * 2];
    f32x4 b = ((const f32x4*)src)[(size_t)i * 2 + 1];
    union { bf16 h[8]; uint4 u; } p;
    p.h[0] = __float2bfloat16(a.x); p.h[1] = __float2bfloat16(a.y);
    p.h[2] = __float2bfloat16(a.z); p.h[3] = __float2bfloat16(a.w);
    p.h[4] = __float2bfloat16(b.x); p.h[5] = __float2bfloat16(b.y);
    p.h[6] = __float2bfloat16(b.z); p.h[7] = __float2bfloat16(b.w);
    ((uint4*)dst)[i] = p.u;
}

// ---------------- m97-style bf16 GEMM: C[M,N] = A[M,K] @ B[N,K]^T ----------------
template<int MODE>
__global__ __launch_bounds__(256)
void gemm_bf16(const bf16* __restrict__ A, const bf16* __restrict__ Bm,
               int K, int N,
               bf16* __restrict__ out0, bf16* __restrict__ out1, bf16* __restrict__ out2,
               float* __restrict__ outf)
{
    __shared__ __align__(16) bf16 As[128 * 32];
    __shared__ __align__(16) bf16 Bs[128 * 32];
    const int tid  = threadIdx.x;
    const int lane = tid & 63;
    const int wid  = tid >> 6;
    const int wr   = wid >> 1, wc = wid & 1;
    const int brow = blockIdx.y * 128;
    const int bcol = blockIdx.x * 128;

    f32x4 acc[4][4];
#pragma unroll
    for (int m = 0; m < 4; ++m)
#pragma unroll
        for (int n = 0; n < 4; ++n) acc[m][n] = (f32x4){0.f, 0.f, 0.f, 0.f};

    const int nkt = K >> 5;
    for (int kt = 0; kt < nkt; ++kt) {
#pragma unroll
        for (int it = 0; it < 2; ++it) {
            int idx = it * 256 + tid;
            int r  = idx >> 2;
            int cb = (idx & 3) << 3;
            const bf16* ga = A  + (size_t)(brow + r) * K + kt * 32 + cb;
            __builtin_amdgcn_global_load_lds((const __attribute__((address_space(1))) void*)ga,
                (__attribute__((address_space(3))) void*)&As[idx * 8], 16, 0, 0);
            const bf16* gb = Bm + (size_t)(bcol + r) * K + kt * 32 + cb;
            __builtin_amdgcn_global_load_lds((const __attribute__((address_space(1))) void*)gb,
                (__attribute__((address_space(3))) void*)&Bs[idx * 8], 16, 0, 0);
        }
        __syncthreads();

        bf16x8s a[4], b[4];
        const int kb = (lane >> 4) << 3;
#pragma unroll
        for (int m = 0; m < 4; ++m) {
            int row = wr * 64 + m * 16 + (lane & 15);
            a[m] = *(const bf16x8s*)&As[row * 32 + kb];
        }
#pragma unroll
        for (int n = 0; n < 4; ++n) {
            int col = wc * 64 + n * 16 + (lane & 15);
            b[n] = *(const bf16x8s*)&Bs[col * 32 + kb];
        }
#pragma unroll
        for (int m = 0; m < 4; ++m)
#pragma unroll
            for (int n = 0; n < 4; ++n)
                acc[m][n] = __builtin_amdgcn_mfma_f32_16x16x32_bf16(a[m], b[n], acc[m][n], 0, 0, 0);
        __syncthreads();
    }

    const int region = bcol >> 10;
#pragma unroll
    for (int m = 0; m < 4; ++m) {
        int row = brow + wr * 64 + m * 16 + ((lane >> 4) << 2);
#pragma unroll
        for (int n = 0; n < 4; ++n) {
            int col = bcol + wc * 64 + n * 16 + (lane & 15);
#pragma unroll
            for (int r = 0; r < 4; ++r) {
                float v = acc[m][n][r];
                size_t rr = (size_t)(row + r);
                if (MODE == 1) {
                    outf[rr * N + col] = v;
                } else {
                    int c = col & 1023;
                    if (region == 0)      out0[rr * 1024 + c] = __float2bfloat16(v);
                    else if (region == 1) out1[rr * 1024 + c] = __float2bfloat16(__expf(v));
                    else                  out2[rr * 1024 + c] = __float2bfloat16(v);
                }
            }
        }
    }
}

// ---------------- per-bucket K-sum (f32) and K^T V outer product (MFMA, bf16 out) ----------------
// grid: bid = bh*64 + n, block 256. ctxb record: [e*64+d] bf16 (= context[d][e]); ksum: [64] f32
__global__ __launch_bounds__(256)
void bucket_kv(const bf16* __restrict__ Kb, const bf16* __restrict__ Vb,
               bf16* __restrict__ ctxb, float* __restrict__ ksum)
{
    __shared__ __align__(16) short k_t[64 * 64];   // [d][s] swizzled
    __shared__ __align__(16) short v_t[64 * 64];   // [e][s] swizzled
    __shared__ __align__(16) float ct[64 * 68];    // [e][d] padded f32
    const int bid = blockIdx.x;
    const int bh = bid >> 6, n = bid & 63;
    const int b = bh >> 4, h = bh & 15;
    const size_t rowbase = (size_t)(b * T_SEQ + n * 64) * 1024 + h * 64;
    const int tid = threadIdx.x;

    // stage K,V transposed into swizzled LDS: thread -> (dc = tid&7, s = tid>>3 [+32])
#pragma unroll
    for (int half = 0; half < 2; ++half) {
        int s  = (tid >> 3) + half * 32;
        int dc = tid & 7;
        bf16x8s kv = *(const bf16x8s*)&Kb[rowbase + (size_t)s * 1024 + dc * 8];
        bf16x8s vv = *(const bf16x8s*)&Vb[rowbase + (size_t)s * 1024 + dc * 8];
        int sc = s >> 3, slo = s & 7;
#pragma unroll
        for (int u = 0; u < 8; ++u) {
            int d = dc * 8 + u;
            int addr = d * 64 + (((sc) ^ swz_f(d)) << 3) + slo;
            k_t[addr] = ((short*)&kv)[u];
            v_t[addr] = ((short*)&vv)[u];
        }
    }
    __syncthreads();

    const int l = tid & 63, w = tid >> 6;

    // ksum[d] = sum_s K[s][d]  (f32) -- wave-parallel over first 64 threads
    if (tid < 64) {
        int d = tid;
        float s = 0.f;
#pragma unroll
        for (int c = 0; c < 8; ++c) {
            bf16x8s kk = *(const bf16x8s*)&k_t[d * 64 + ((c ^ swz_f(d)) << 3)];
#pragma unroll
            for (int u = 0; u < 8; ++u) s += bf2f(((short*)&kk)[u]);
        }
        ksum[(size_t)bid * 64 + d] = s;
    }

    // MFMA: C[d][e] = sum_s K[s][d] V[s][e]; wave w owns d-rows [16w,16w+16)
    f32x4 acc[4];
#pragma unroll
    for (int i = 0; i < 4; ++i) acc[i] = (f32x4){0.f, 0.f, 0.f, 0.f};
    bf16x8s afr[2], bfr[2][4];
#pragma unroll
    for (int kk = 0; kk < 2; ++kk) {
        int cc = kk * 4 + (l >> 4);
        int r = w * 16 + (l & 15);
        afr[kk] = *(const bf16x8s*)&k_t[r * 64 + ((cc ^ swz_f(r)) << 3)];
#pragma unroll
        for (int n4 = 0; n4 < 4; ++n4) {
            int e = n4 * 16 + (l & 15);
            bfr[kk][n4] = *(const bf16x8s*)&v_t[e * 64 + ((cc ^ swz_f(e)) << 3)];
        }
    }
#pragma unroll
    for (int kk = 0; kk < 2; ++kk)
#pragma unroll
        for (int n4 = 0; n4 < 4; ++n4)
            acc[n4] = __builtin_amdgcn_mfma_f32_16x16x32_bf16(afr[kk], bfr[kk][n4], acc[n4], 0, 0, 0);

    // store C to ct[e][d]: col e = n4*16+(l&15); rows d = w*16 + (l>>4)*4 + r (4 consecutive)
#pragma unroll
    for (int n4 = 0; n4 < 4; ++n4) {
        int e = n4 * 16 + (l & 15);
        int d0 = w * 16 + ((l >> 4) << 2);
        *(f32x4*)&ct[e * 68 + d0] = acc[n4];
    }
    __syncthreads();

    // copy out: record [e*64+d] bf16
#pragma unroll
    for (int j = 0; j < 2; ++j) {
        int i = tid + 256 * j;
        int e = i >> 3, d0 = (i & 7) * 8;
        f32x4 lo = *(const f32x4*)&ct[e * 68 + d0];
        f32x4 hi = *(const f32x4*)&ct[e * 68 + d0 + 4];
        union { short h[8]; uint4 u; } p;
        p.h[0] = f2bf(lo.x); p.h[1] = f2bf(lo.y); p.h[2] = f2bf(lo.z); p.h[3] = f2bf(lo.w);
        p.h[4] = f2bf(hi.x); p.h[5] = f2bf(hi.y); p.h[6] = f2bf(hi.z); p.h[7] = f2bf(hi.w);
        ((uint4*)&ctxb[(size_t)bid * 4096])[i] = p.u;
    }
}

// ---------------- exclusive cumsum over buckets ----------------
// grid (5, 64): x<4 -> ctx chains (bf16 in, f32 accum, bf16 out); x==4 -> ksum chains (f32)
__global__ void cumsum_excl(const bf16* __restrict__ ctxb, const float* __restrict__ ksum,
                            bf16* __restrict__ ctp, float* __restrict__ ksump)
{
    const int bh = blockIdx.y;
    if (blockIdx.x == 4) {
        int d = threadIdx.x;
        if (d >= 64) return;
        float run = 0.f;
        for (int j = 0; j < 64; ++j) {
            size_t idx = (size_t)(bh * 64 + j) * 64 + d;
            float v = ksum[idx];
            ksump[idx] = run;
            run += v;
        }
        return;
    }
    int e0 = (blockIdx.x * 256 + threadIdx.x) * 4;
    float r0 = 0.f, r1 = 0.f, r2 = 0.f, r3 = 0.f;
    for (int j = 0; j < 64; ++j) {
        size_t idx = (size_t)(bh * 64 + j) * 4096 + e0;
        ushort4 v = *(const ushort4*)&ctxb[idx];
        ushort4 o;
        o.x = (ushort)f2bf(r0); o.y = (ushort)f2bf(r1);
        o.z = (ushort)f2bf(r2); o.w = (ushort)f2bf(r3);
        *(ushort4*)&ctp[idx] = o;
        r0 += bf2f((short)v.x); r1 += bf2f((short)v.y);
        r2 += bf2f((short)v.z); r3 += bf2f((short)v.w);
    }
}

// ---------------- softmax(q) + den + attn = q @ ctx * Dinv (MFMA) ----------------
__global__ __launch_bounds__(256)
void bucket_attn(const bf16* __restrict__ Qb, const bf16* __restrict__ ctp,
                 const float* __restrict__ ksump, bf16* __restrict__ attn)
{
    __shared__ __align__(16) short q_bf[64 * 64];   // [s][d] swizzled
    __shared__ __align__(16) short ct_bf[64 * 64];  // [e][d] swizzled
    __shared__ __align__(16) short at_s[64 * 72];   // [s][e] out staging
    __shared__ float dinv_s[64];
    __shared__ float ksum_s[64];
    const int bid = blockIdx.x;
    const int bh = bid >> 6, n = bid & 63;
    const int b = bh >> 4, h = bh & 15;
    const size_t rowbase = (size_t)(b * T_SEQ + n * 64) * 1024 + h * 64;
    const int tid = threadIdx.x;
    const int l = tid & 63, w = tid >> 6;

    // stage ct (exclusive-prefix context^T, bf16) into swizzled LDS
#pragma unroll
    for (int j = 0; j < 2; ++j) {
        int i = tid + 256 * j;
        int e = i >> 3, dc = i & 7;
        bf16x8s cv = *(const bf16x8s*)&ctp[(size_t)bid * 4096 + e * 64 + dc * 8];
        *(bf16x8s*)&ct_bf[e * 64 + ((dc ^ swz_f(e)) << 3)] = cv;
    }
    if (tid < 64) ksum_s[tid] = ksump[(size_t)bid * 64 + tid];
    __syncthreads();   // ksum_s ready for den below

    // softmax per row (lane = d), fold in den + dinv, write q_bf swizzled
#pragma unroll
    for (int i = 0; i < 16; ++i) {
        int s = w * 16 + i;
        float x = bf2f(*(const short*)&Qb[rowbase + (size_t)s * 1024 + l]);
        float mx = x;
#pragma unroll
        for (int off = 32; off; off >>= 1) mx = fmaxf(mx, __shfl_xor(mx, off));
        float ex = __expf(x - mx);
        float sm = ex;
#pragma unroll
        for (int off = 32; off; off >>= 1) sm += __shfl_xor(sm, off);
        float qv = ex / sm * 0.125f;
        float dp = qv * ksum_s[l];
#pragma unroll
        for (int off = 32; off; off >>= 1) dp += __shfl_xor(dp, off);
        if (l == 0) dinv_s[s] = 1.f / fmaxf(dp, 1e-6f);
        q_bf[s * 64 + ((((l >> 3)) ^ swz_f(s)) << 3) + (l & 7)] = f2bf(qv);
    }
    __syncthreads();

    // MFMA: attn[s][e] = sum_d q[s][d] * ctx[d][e]; wave w owns s-rows [16w,16w+16)
    f32x4 acc[4];
#pragma unroll
    for (int i = 0; i < 4; ++i) acc[i] = (f32x4){0.f, 0.f, 0.f, 0.f};
    bf16x8s afr[2], bfr[2][4];
#pragma unroll
    for (int kk = 0; kk < 2; ++kk) {
        int cc = kk * 4 + (l >> 4);
        int r = w * 16 + (l & 15);
        afr[kk] = *(const bf16x8s*)&q_bf[r * 64 + ((cc ^ swz_f(r)) << 3)];
#pragma unroll
        for (int n4 = 0; n4 < 4; ++n4) {
            int e = n4 * 16 + (l & 15);
            bfr[kk][n4] = *(const bf16x8s*)&ct_bf[e * 64 + ((cc ^ swz_f(e)) << 3)];
        }
    }
#pragma unroll
    for (int kk = 0; kk < 2; ++kk)
#pragma unroll
        for (int n4 = 0; n4 < 4; ++n4)
            acc[n4] = __builtin_amdgcn_mfma_f32_16x16x32_bf16(afr[kk], bfr[kk][n4], acc[n4], 0, 0, 0);

    // scale by dinv[row] and scatter to at_s[s][e]
#pragma unroll
    for (int n4 = 0; n4 < 4; ++n4) {
        int e = n4 * 16 + (l & 15);
#pragma unroll
        for (int r = 0; r < 4; ++r) {
            int s = w * 16 + ((l >> 4) << 2) + r;
            at_s[s * 72 + e] = f2bf(acc[n4][r] * dinv_s[s]);
        }
    }
    __syncthreads();

    // coalesced copy out
#pragma unroll
    for (int j = 0; j < 2; ++j) {
        int i = tid + 256 * j;
        int s = i >> 3, c = i & 7;
        bf16x8s v = *(const bf16x8s*)&at_s[s * 72 + c * 8];
        *(bf16x8s*)&attn[rowbase + (size_t)s * 1024 + c * 8] = v;
    }
}

// ---------------- launch ----------------
extern "C" void kernel_launch(void* const* d_in, const int* in_sizes, int n_in,
                              void* d_out, int out_size, void* d_ws, size_t ws_size,
                              hipStream_t stream)
{
    const float* x    = (const float*)d_in[0];
    const float* Wqkv = (const float*)d_in[1];
    const float* Wout = (const float*)d_in[2];

    char* ws = (char*)d_ws;
    size_t off = 0;
    auto alloc = [&](size_t bytes) { void* p = ws + off; off += (bytes + 255) & ~(size_t)255; return p; };
    bf16*  xb    = (bf16*)alloc((size_t)16384 * 1024 * 2);
    bf16*  wqkvb = (bf16*)alloc((size_t)3072 * 1024 * 2);
    bf16*  woutb = (bf16*)alloc((size_t)1024 * 1024 * 2);
    bf16*  Qb    = (bf16*)alloc((size_t)16384 * 1024 * 2);
    bf16*  Kb    = (bf16*)alloc((size_t)16384 * 1024 * 2);
    bf16*  Vb    = (bf16*)alloc((size_t)16384 * 1024 * 2);
    bf16*  ctxb  = (bf16*)alloc((size_t)4096 * 4096 * 2);
    float* ksum  = (float*)alloc((size_t)4096 * 64 * 4);
    bf16*  ctp   = (bf16*)alloc((size_t)4096 * 4096 * 2);
    float* ksump = (float*)alloc((size_t)4096 * 64 * 4);
    bf16*  attnb = xb;                       // xb dead after GEMM1 -> reuse
    float* outf  = (float*)d_out;

    cvt_f32_bf16<<<dim3(16384 * 1024 / 8 / 256), 256, 0, stream>>>(x, xb, 16384 * 1024 / 8);
    cvt_f32_bf16<<<dim3(3072 * 1024 / 8 / 256), 256, 0, stream>>>(Wqkv, wqkvb, 3072 * 1024 / 8);
    cvt_f32_bf16<<<dim3(1024 * 1024 / 8 / 256), 256, 0, stream>>>(Wout, woutb, 1024 * 1024 / 8);

    gemm_bf16<0><<<dim3(24, 128), 256, 0, stream>>>(xb, wqkvb, 1024, 3072, Qb, Kb, Vb, nullptr);
    bucket_kv<<<dim3(4096), 256, 0, stream>>>(Kb, Vb, ctxb, ksum);
    cumsum_excl<<<dim3(5, 64), 256, 0, stream>>>(ctxb, ksum, ctp, ksump);
    bucket_attn<<<dim3(4096), 256, 0, stream>>>(Qb, ctp, ksump, attnb);
    gemm_bf16<1><<<dim3(8, 128), 256, 0, stream>>>(attnb, woutb, 1024, 1024, nullptr, nullptr, nullptr, outf);
}

// Round 4
// 283.753 us; speedup vs baseline: 1.3870x; 1.1533x over previous
//
#include <hip/hip_runtime.h>
#include <hip/hip_bf16.h>
#include <math.h>

typedef __hip_bfloat16 bf16;
typedef __attribute__((ext_vector_type(4))) float f32x4;
typedef __attribute__((ext_vector_type(8))) short bf16x8s;

#define T_SEQ 4096
#define MFMA16(a, b, c) __builtin_amdgcn_mfma_f32_16x16x32_bf16(a, b, c, 0, 0, 0)

static __device__ __forceinline__ float bf2f(short u) {
    return __uint_as_float(((unsigned int)(unsigned short)u) << 16);
}
static __device__ __forceinline__ short f2bf(float f) {
    bf16 h = __float2bfloat16(f);
    union { bf16 b; short s; } c; c.b = h; return c.s;
}
static __device__ __forceinline__ int swz_f(int r) { return (r & 7) ^ (r >> 3); }

// ---------------- f32 -> bf16 conversion (vectorized) ----------------
__global__ void cvt_f32_bf16(const float* __restrict__ src, bf16* __restrict__ dst, int n8) {
    int i = blockIdx.x * 256 + threadIdx.x;
    if (i >= n8) return;
    f32x4 a = ((const f32x4*)src)[(size_t)i * 2];
    f32x4 b = ((const f32x4*)src)[(size_t)i * 2 + 1];
    union { bf16 h[8]; uint4 u; } p;
    p.h[0] = __float2bfloat16(a.x); p.h[1] = __float2bfloat16(a.y);
    p.h[2] = __float2bfloat16(a.z); p.h[3] = __float2bfloat16(a.w);
    p.h[4] = __float2bfloat16(b.x); p.h[5] = __float2bfloat16(b.y);
    p.h[6] = __float2bfloat16(b.z); p.h[7] = __float2bfloat16(b.w);
    ((uint4*)dst)[i] = p.u;
}

// ============ 256x256 tile, BK=64, 8-wave deep-pipelined bf16 GEMM ============
// C[M,N] = A[M,K] @ B[N,K]^T.
// MODE 0: N=3072 qkv epilogue -> Q (raw), K (exp), V (raw) bf16 [M,1024] each.
// MODE 1: f32 output.
// Schedule: 4 phases/K-tile; per phase: ds_read frags | stage one 16KB k-half of
// tile t+1 | counted vmcnt(4) at phases 1,3 | s_barrier | lgkmcnt(0) | 16 MFMA.
// Load ledger (per thread, 2 loads per half-stage, FIFO):
//   tile t stages: p0:Ak0(t+1) p1:Bk0(t+1) p2:Ak1(t+1) p3:Bk1(t+1)
//   vmcnt(4)@p1 completes Ak1(t),Bk1(t) (needed by p2/p3 reads);
//   vmcnt(4)@p3 completes Ak0(t+1),Bk0(t+1) (needed by next tile p0/p1 reads).
// In-flight loads oscillate 4..8, never drained to 0 (T4).
template<int MODE>
__global__ __launch_bounds__(512, 2)
void gemm256(const bf16* __restrict__ A, const bf16* __restrict__ Bm,
             int K, int N,
             bf16* __restrict__ out0, bf16* __restrict__ out1, bf16* __restrict__ out2,
             float* __restrict__ outf)
{
    __shared__ __align__(16) short As[2][2][256 * 32];   // [buf][khalf][row*32+col]
    __shared__ __align__(16) short Bs[2][2][256 * 32];
    const int tid  = threadIdx.x;
    const int l    = tid & 63;
    const int wid  = tid >> 6;           // 0..7
    const int wr   = wid >> 2;           // 0..1 : M-wave (128 rows each)
    const int wc   = wid & 3;            // 0..3 : N-wave (64 cols each)
    const int brow = blockIdx.y * 256;
    const int bcol = blockIdx.x * 256;
    const int nkt  = K >> 6;

    const bf16* Ab = A  + (size_t)brow * K;
    const bf16* Bb = Bm + (size_t)bcol * K;
    const int srow   = tid >> 2;         // staging: 0..127
    const int schunk = tid & 3;

    // stage one 16KB k-half (2 x global_load_lds x16B per thread), source-swizzled
#define STAGE(dstArr, srcp, buf, kh, kt)                                          \
    {                                                                             \
        _Pragma("unroll")                                                         \
        for (int j = 0; j < 2; ++j) {                                             \
            int row = j * 128 + srow;                                             \
            int cs  = schunk ^ ((row >> 1) & 3);                                  \
            const bf16* g = srcp + (size_t)row * K + (kt) * 64 + (kh) * 32 + cs * 8; \
            __builtin_amdgcn_global_load_lds(                                     \
                (const __attribute__((address_space(1))) void*)g,                 \
                (__attribute__((address_space(3))) void*)&dstArr[buf][kh][(j * 512 + tid) * 8], \
                16, 0, 0);                                                        \
        }                                                                         \
    }

    f32x4 acc[8][4];
#pragma unroll
    for (int m = 0; m < 8; ++m)
#pragma unroll
        for (int n = 0; n < 4; ++n) acc[m][n] = (f32x4){0.f, 0.f, 0.f, 0.f};

    // ---- prologue: stage tile 0 fully; complete k0 halves ----
    STAGE(As, Ab, 0, 0, 0);
    STAGE(Bs, Bb, 0, 0, 0);
    STAGE(As, Ab, 0, 1, 0);
    STAGE(Bs, Bb, 0, 1, 0);
    asm volatile("s_waitcnt vmcnt(4)" ::: "memory");
    __builtin_amdgcn_s_barrier();

    for (int t = 0; t < nkt; ++t) {
        const int cur = t & 1, nxt = cur ^ 1;
        const bool pf = (t + 1 < nkt);
        bf16x8s bfr[4], afr[4];

        // read helpers (inline): frag at (buf, ksub s, row r): chunk p = (l>>4) ^ ((r>>1)&3)
#define RDA(buf, s, m_) (*(const bf16x8s*)&As[buf][s][(wr * 128 + (m_) * 16 + (l & 15)) * 32 + (((l >> 4) ^ (((wr * 128 + (m_) * 16 + (l & 15)) >> 1) & 3)) * 8)])
#define RDB(buf, s, n_) (*(const bf16x8s*)&Bs[buf][s][(wc * 64 + (n_) * 16 + (l & 15)) * 32 + (((l >> 4) ^ (((wc * 64 + (n_) * 16 + (l & 15)) >> 1) & 3)) * 8)])

        // ---------- phase 0: ksub0, m0-3 ----------
#pragma unroll
        for (int n = 0; n < 4; ++n) bfr[n] = RDB(cur, 0, n);
#pragma unroll
        for (int m = 0; m < 4; ++m) afr[m] = RDA(cur, 0, m);
        if (pf) STAGE(As, Ab, nxt, 0, t + 1);
        __builtin_amdgcn_s_barrier();
        asm volatile("s_waitcnt lgkmcnt(0)" ::: "memory");
        __builtin_amdgcn_sched_barrier(0);
        __builtin_amdgcn_s_setprio(1);
#pragma unroll
        for (int m = 0; m < 4; ++m)
#pragma unroll
            for (int n = 0; n < 4; ++n) acc[m][n] = MFMA16(afr[m], bfr[n], acc[m][n]);
        __builtin_amdgcn_s_setprio(0);
        __builtin_amdgcn_s_barrier();

        // ---------- phase 1: ksub0, m4-7 ----------
#pragma unroll
        for (int m = 0; m < 4; ++m) afr[m] = RDA(cur, 0, m + 4);
        if (pf) STAGE(Bs, Bb, nxt, 0, t + 1);
        asm volatile("s_waitcnt vmcnt(4)" ::: "memory");
        __builtin_amdgcn_s_barrier();
        asm volatile("s_waitcnt lgkmcnt(0)" ::: "memory");
        __builtin_amdgcn_sched_barrier(0);
        __builtin_amdgcn_s_setprio(1);
#pragma unroll
        for (int m = 0; m < 4; ++m)
#pragma unroll
            for (int n = 0; n < 4; ++n) acc[m + 4][n] = MFMA16(afr[m], bfr[n], acc[m + 4][n]);
        __builtin_amdgcn_s_setprio(0);
        __builtin_amdgcn_s_barrier();

        // ---------- phase 2: ksub1, m0-3 ----------
#pragma unroll
        for (int n = 0; n < 4; ++n) bfr[n] = RDB(cur, 1, n);
#pragma unroll
        for (int m = 0; m < 4; ++m) afr[m] = RDA(cur, 1, m);
        if (pf) STAGE(As, Ab, nxt, 1, t + 1);
        __builtin_amdgcn_s_barrier();
        asm volatile("s_waitcnt lgkmcnt(0)" ::: "memory");
        __builtin_amdgcn_sched_barrier(0);
        __builtin_amdgcn_s_setprio(1);
#pragma unroll
        for (int m = 0; m < 4; ++m)
#pragma unroll
            for (int n = 0; n < 4; ++n) acc[m][n] = MFMA16(afr[m], bfr[n], acc[m][n]);
        __builtin_amdgcn_s_setprio(0);
        __builtin_amdgcn_s_barrier();

        // ---------- phase 3: ksub1, m4-7 ----------
#pragma unroll
        for (int m = 0; m < 4; ++m) afr[m] = RDA(cur, 1, m + 4);
        if (pf) STAGE(Bs, Bb, nxt, 1, t + 1);
        asm volatile("s_waitcnt vmcnt(4)" ::: "memory");
        __builtin_amdgcn_s_barrier();
        asm volatile("s_waitcnt lgkmcnt(0)" ::: "memory");
        __builtin_amdgcn_sched_barrier(0);
        __builtin_amdgcn_s_setprio(1);
#pragma unroll
        for (int m = 0; m < 4; ++m)
#pragma unroll
            for (int n = 0; n < 4; ++n) acc[m + 4][n] = MFMA16(afr[m], bfr[n], acc[m + 4][n]);
        __builtin_amdgcn_s_setprio(0);
        __builtin_amdgcn_s_barrier();
    }

    // ---------- epilogue: C mapping col=lane&15, row=(lane>>4)*4+r ----------
    const int region = bcol >> 10;   // uniform per block (256 | 1024)
#pragma unroll
    for (int m = 0; m < 8; ++m) {
        int row = brow + wr * 128 + m * 16 + ((l >> 4) << 2);
#pragma unroll
        for (int n = 0; n < 4; ++n) {
            int col = bcol + wc * 64 + n * 16 + (l & 15);
#pragma unroll
            for (int r = 0; r < 4; ++r) {
                float v = acc[m][n][r];
                size_t rr = (size_t)(row + r);
                if (MODE == 1) {
                    outf[rr * N + col] = v;
                } else {
                    int c = col & 1023;
                    if (region == 0)      out0[rr * 1024 + c] = __float2bfloat16(v);
                    else if (region == 1) out1[rr * 1024 + c] = __float2bfloat16(__expf(v));
                    else                  out2[rr * 1024 + c] = __float2bfloat16(v);
                }
            }
        }
    }
#undef STAGE
#undef RDA
#undef RDB
}

// ---------------- per-bucket K-sum (f32) and K^T V outer product (MFMA, bf16 out) ----------------
__global__ __launch_bounds__(256)
void bucket_kv(const bf16* __restrict__ Kb, const bf16* __restrict__ Vb,
               bf16* __restrict__ ctxb, float* __restrict__ ksum)
{
    __shared__ __align__(16) short k_t[64 * 64];   // [d][s] swizzled
    __shared__ __align__(16) short v_t[64 * 64];   // [e][s] swizzled
    __shared__ __align__(16) float ct[64 * 68];    // [e][d] padded f32
    const int bid = blockIdx.x;
    const int bh = bid >> 6, n = bid & 63;
    const int b = bh >> 4, h = bh & 15;
    const size_t rowbase = (size_t)(b * T_SEQ + n * 64) * 1024 + h * 64;
    const int tid = threadIdx.x;

#pragma unroll
    for (int half = 0; half < 2; ++half) {
        int s  = (tid >> 3) + half * 32;
        int dc = tid & 7;
        bf16x8s kv = *(const bf16x8s*)&Kb[rowbase + (size_t)s * 1024 + dc * 8];
        bf16x8s vv = *(const bf16x8s*)&Vb[rowbase + (size_t)s * 1024 + dc * 8];
        int sc = s >> 3, slo = s & 7;
#pragma unroll
        for (int u = 0; u < 8; ++u) {
            int d = dc * 8 + u;
            int addr = d * 64 + (((sc) ^ swz_f(d)) << 3) + slo;
            k_t[addr] = ((short*)&kv)[u];
            v_t[addr] = ((short*)&vv)[u];
        }
    }
    __syncthreads();

    const int l = tid & 63, w = tid >> 6;

    if (tid < 64) {
        int d = tid;
        float s = 0.f;
#pragma unroll
        for (int c = 0; c < 8; ++c) {
            bf16x8s kk = *(const bf16x8s*)&k_t[d * 64 + ((c ^ swz_f(d)) << 3)];
#pragma unroll
            for (int u = 0; u < 8; ++u) s += bf2f(((short*)&kk)[u]);
        }
        ksum[(size_t)bid * 64 + d] = s;
    }

    f32x4 acc[4];
#pragma unroll
    for (int i = 0; i < 4; ++i) acc[i] = (f32x4){0.f, 0.f, 0.f, 0.f};
    bf16x8s afr[2], bfr[2][4];
#pragma unroll
    for (int kk = 0; kk < 2; ++kk) {
        int cc = kk * 4 + (l >> 4);
        int r = w * 16 + (l & 15);
        afr[kk] = *(const bf16x8s*)&k_t[r * 64 + ((cc ^ swz_f(r)) << 3)];
#pragma unroll
        for (int n4 = 0; n4 < 4; ++n4) {
            int e = n4 * 16 + (l & 15);
            bfr[kk][n4] = *(const bf16x8s*)&v_t[e * 64 + ((cc ^ swz_f(e)) << 3)];
        }
    }
#pragma unroll
    for (int kk = 0; kk < 2; ++kk)
#pragma unroll
        for (int n4 = 0; n4 < 4; ++n4)
            acc[n4] = MFMA16(afr[kk], bfr[kk][n4], acc[n4]);

#pragma unroll
    for (int n4 = 0; n4 < 4; ++n4) {
        int e = n4 * 16 + (l & 15);
        int d0 = w * 16 + ((l >> 4) << 2);
        *(f32x4*)&ct[e * 68 + d0] = acc[n4];
    }
    __syncthreads();

#pragma unroll
    for (int j = 0; j < 2; ++j) {
        int i = tid + 256 * j;
        int e = i >> 3, d0 = (i & 7) * 8;
        f32x4 lo = *(const f32x4*)&ct[e * 68 + d0];
        f32x4 hi = *(const f32x4*)&ct[e * 68 + d0 + 4];
        union { short h[8]; uint4 u; } p;
        p.h[0] = f2bf(lo.x); p.h[1] = f2bf(lo.y); p.h[2] = f2bf(lo.z); p.h[3] = f2bf(lo.w);
        p.h[4] = f2bf(hi.x); p.h[5] = f2bf(hi.y); p.h[6] = f2bf(hi.z); p.h[7] = f2bf(hi.w);
        ((uint4*)&ctxb[(size_t)bid * 4096])[i] = p.u;
    }
}

// ---------------- exclusive cumsum over buckets ----------------
__global__ void cumsum_excl(const bf16* __restrict__ ctxb, const float* __restrict__ ksum,
                            bf16* __restrict__ ctp, float* __restrict__ ksump)
{
    const int bh = blockIdx.y;
    if (blockIdx.x == 4) {
        int d = threadIdx.x;
        if (d >= 64) return;
        float run = 0.f;
        for (int j = 0; j < 64; ++j) {
            size_t idx = (size_t)(bh * 64 + j) * 64 + d;
            float v = ksum[idx];
            ksump[idx] = run;
            run += v;
        }
        return;
    }
    int e0 = (blockIdx.x * 256 + threadIdx.x) * 4;
    float r0 = 0.f, r1 = 0.f, r2 = 0.f, r3 = 0.f;
    for (int j = 0; j < 64; ++j) {
        size_t idx = (size_t)(bh * 64 + j) * 4096 + e0;
        ushort4 v = *(const ushort4*)&ctxb[idx];
        ushort4 o;
        o.x = (ushort)f2bf(r0); o.y = (ushort)f2bf(r1);
        o.z = (ushort)f2bf(r2); o.w = (ushort)f2bf(r3);
        *(ushort4*)&ctp[idx] = o;
        r0 += bf2f((short)v.x); r1 += bf2f((short)v.y);
        r2 += bf2f((short)v.z); r3 += bf2f((short)v.w);
    }
}

// ---------------- softmax(q) + den + attn = q @ ctx * Dinv (MFMA) ----------------
__global__ __launch_bounds__(256)
void bucket_attn(const bf16* __restrict__ Qb, const bf16* __restrict__ ctp,
                 const float* __restrict__ ksump, bf16* __restrict__ attn)
{
    __shared__ __align__(16) short q_bf[64 * 64];
    __shared__ __align__(16) short ct_bf[64 * 64];
    __shared__ __align__(16) short at_s[64 * 72];
    __shared__ float dinv_s[64];
    __shared__ float ksum_s[64];
    const int bid = blockIdx.x;
    const int bh = bid >> 6, n = bid & 63;
    const int b = bh >> 4, h = bh & 15;
    const size_t rowbase = (size_t)(b * T_SEQ + n * 64) * 1024 + h * 64;
    const int tid = threadIdx.x;
    const int l = tid & 63, w = tid >> 6;

#pragma unroll
    for (int j = 0; j < 2; ++j) {
        int i = tid + 256 * j;
        int e = i >> 3, dc = i & 7;
        bf16x8s cv = *(const bf16x8s*)&ctp[(size_t)bid * 4096 + e * 64 + dc * 8];
        *(bf16x8s*)&ct_bf[e * 64 + ((dc ^ swz_f(e)) << 3)] = cv;
    }
    if (tid < 64) ksum_s[tid] = ksump[(size_t)bid * 64 + tid];
    __syncthreads();

#pragma unroll
    for (int i = 0; i < 16; ++i) {
        int s = w * 16 + i;
        float x = bf2f(*(const short*)&Qb[rowbase + (size_t)s * 1024 + l]);
        float mx = x;
#pragma unroll
        for (int off = 32; off; off >>= 1) mx = fmaxf(mx, __shfl_xor(mx, off));
        float ex = __expf(x - mx);
        float sm = ex;
#pragma unroll
        for (int off = 32; off; off >>= 1) sm += __shfl_xor(sm, off);
        float qv = ex / sm * 0.125f;
        float dp = qv * ksum_s[l];
#pragma unroll
        for (int off = 32; off; off >>= 1) dp += __shfl_xor(dp, off);
        if (l == 0) dinv_s[s] = 1.f / fmaxf(dp, 1e-6f);
        q_bf[s * 64 + ((((l >> 3)) ^ swz_f(s)) << 3) + (l & 7)] = f2bf(qv);
    }
    __syncthreads();

    f32x4 acc[4];
#pragma unroll
    for (int i = 0; i < 4; ++i) acc[i] = (f32x4){0.f, 0.f, 0.f, 0.f};
    bf16x8s afr[2], bfr[2][4];
#pragma unroll
    for (int kk = 0; kk < 2; ++kk) {
        int cc = kk * 4 + (l >> 4);
        int r = w * 16 + (l & 15);
        afr[kk] = *(const bf16x8s*)&q_bf[r * 64 + ((cc ^ swz_f(r)) << 3)];
#pragma unroll
        for (int n4 = 0; n4 < 4; ++n4) {
            int e = n4 * 16 + (l & 15);
            bfr[kk][n4] = *(const bf16x8s*)&ct_bf[e * 64 + ((cc ^ swz_f(e)) << 3)];
        }
    }
#pragma unroll
    for (int kk = 0; kk < 2; ++kk)
#pragma unroll
        for (int n4 = 0; n4 < 4; ++n4)
            acc[n4] = MFMA16(afr[kk], bfr[kk][n4], acc[n4]);

#pragma unroll
    for (int n4 = 0; n4 < 4; ++n4) {
        int e = n4 * 16 + (l & 15);
#pragma unroll
        for (int r = 0; r < 4; ++r) {
            int s = w * 16 + ((l >> 4) << 2) + r;
            at_s[s * 72 + e] = f2bf(acc[n4][r] * dinv_s[s]);
        }
    }
    __syncthreads();

#pragma unroll
    for (int j = 0; j < 2; ++j) {
        int i = tid + 256 * j;
        int s = i >> 3, c = i & 7;
        bf16x8s v = *(const bf16x8s*)&at_s[s * 72 + c * 8];
        *(bf16x8s*)&attn[rowbase + (size_t)s * 1024 + c * 8] = v;
    }
}

// ---------------- launch ----------------
extern "C" void kernel_launch(void* const* d_in, const int* in_sizes, int n_in,
                              void* d_out, int out_size, void* d_ws, size_t ws_size,
                              hipStream_t stream)
{
    const float* x    = (const float*)d_in[0];
    const float* Wqkv = (const float*)d_in[1];
    const float* Wout = (const float*)d_in[2];

    char* ws = (char*)d_ws;
    size_t off = 0;
    auto alloc = [&](size_t bytes) { void* p = ws + off; off += (bytes + 255) & ~(size_t)255; return p; };
    bf16*  xb    = (bf16*)alloc((size_t)16384 * 1024 * 2);
    bf16*  wqkvb = (bf16*)alloc((size_t)3072 * 1024 * 2);
    bf16*  woutb = (bf16*)alloc((size_t)1024 * 1024 * 2);
    bf16*  Qb    = (bf16*)alloc((size_t)16384 * 1024 * 2);
    bf16*  Kb    = (bf16*)alloc((size_t)16384 * 1024 * 2);
    bf16*  Vb    = (bf16*)alloc((size_t)16384 * 1024 * 2);
    bf16*  ctxb  = (bf16*)alloc((size_t)4096 * 4096 * 2);
    float* ksum  = (float*)alloc((size_t)4096 * 64 * 4);
    bf16*  ctp   = (bf16*)alloc((size_t)4096 * 4096 * 2);
    float* ksump = (float*)alloc((size_t)4096 * 64 * 4);
    bf16*  attnb = xb;                       // xb dead after GEMM1 -> reuse
    float* outf  = (float*)d_out;

    cvt_f32_bf16<<<dim3(16384 * 1024 / 8 / 256), 256, 0, stream>>>(x, xb, 16384 * 1024 / 8);
    cvt_f32_bf16<<<dim3(3072 * 1024 / 8 / 256), 256, 0, stream>>>(Wqkv, wqkvb, 3072 * 1024 / 8);
    cvt_f32_bf16<<<dim3(1024 * 1024 / 8 / 256), 256, 0, stream>>>(Wout, woutb, 1024 * 1024 / 8);

    gemm256<0><<<dim3(12, 64), 512, 0, stream>>>(xb, wqkvb, 1024, 3072, Qb, Kb, Vb, nullptr);
    bucket_kv<<<dim3(4096), 256, 0, stream>>>(Kb, Vb, ctxb, ksum);
    cumsum_excl<<<dim3(5, 64), 256, 0, stream>>>(ctxb, ksum, ctp, ksump);
    bucket_attn<<<dim3(4096), 256, 0, stream>>>(Qb, ctp, ksump, attnb);
    gemm256<1><<<dim3(4, 64), 512, 0, stream>>>(attnb, woutb, 1024, 1024, nullptr, nullptr, nullptr, outf);
}